// Round 16
// baseline (33.440 us; speedup 1.0000x reference)
//
#include <hip/hip_runtime.h>
#include <math.h>

#define BLK 100          // BLOCK
#define NF  128          // N_freqs
#define NTOT (NF * BLK)  // 12800
#define P   104          // LDS pitch (floats): rows 16B-aligned (416B)
#define NT  512          // 8 waves = 2 waves/SIMD (measured best)

__device__ __forceinline__ float4 fnma4(float4 v, float s, const float4 p) {
    v.x -= s * p.x; v.y -= s * p.y; v.z -= s * p.z; v.w -= s * p.w; return v;
}
__device__ __forceinline__ float4 mul4(float4 v, float s) {
    v.x *= s; v.y *= s; v.z *= s; v.w *= s; return v;
}

#define LD4(r, c4) (*reinterpret_cast<float4*>(&a[(r) * P + 4 * (c4)]))

// 4x4 panel at rows kb..kb+3, panel col group gq, lane col group gg ->
// Q0..Q3 = panel^-1 * P_raw; accumulates mant/e2/lneg. Reads LDS, per-lane ops.
#define PANEL_Q(kb, gq)                                                        \
    {                                                                          \
        float4 pp0 = LD4((kb) + 0, (gq));                                      \
        float4 pp1 = LD4((kb) + 1, (gq));                                      \
        float4 pp2 = LD4((kb) + 2, (gq));                                      \
        float4 pp3 = LD4((kb) + 3, (gq));                                      \
        float4 P0  = LD4((kb) + 0, gg);                                        \
        float4 P1  = LD4((kb) + 1, gg);                                        \
        float4 P2  = LD4((kb) + 2, gg);                                        \
        float4 P3  = LD4((kb) + 3, gg);                                        \
        const float d0 = pp0.x, r0i = 1.0f / d0;                               \
        float l;                                                               \
        l = pp1.x * r0i;  pp1 = fnma4(pp1, l, pp0);  P1 = fnma4(P1, l, P0);    \
        const float d1 = pp1.y, r1i = 1.0f / d1;                               \
        l = pp2.x * r0i;  pp2 = fnma4(pp2, l, pp0);  P2 = fnma4(P2, l, P0);    \
        l = pp2.y * r1i;  pp2 = fnma4(pp2, l, pp1);  P2 = fnma4(P2, l, P1);    \
        const float d2 = pp2.z, r2i = 1.0f / d2;                               \
        l = pp3.x * r0i;  pp3 = fnma4(pp3, l, pp0);  P3 = fnma4(P3, l, P0);    \
        l = pp3.y * r1i;  pp3 = fnma4(pp3, l, pp1);  P3 = fnma4(P3, l, P1);    \
        l = pp3.z * r2i;  pp3 = fnma4(pp3, l, pp2);  P3 = fnma4(P3, l, P2);    \
        const float d3 = pp3.w, r3i = 1.0f / d3;                               \
        Q3 = mul4(P3, r3i);                                                    \
        Q2 = mul4(fnma4(P2, pp2.w, Q3), r2i);                                  \
        Q1 = mul4(fnma4(fnma4(P1, pp1.z, Q2), pp1.w, Q3), r1i);                \
        Q0 = mul4(fnma4(fnma4(fnma4(P0, pp0.y, Q1), pp0.z, Q2), pp0.w, Q3), r0i); \
        mant *= d0 * d1 * d2 * d3;                                             \
        { int t_; mant = frexpf(mant, &t_); e2 += t_; }                        \
        lneg += (d0 < 0.0f) + (d1 < 0.0f) + (d2 < 0.0f) + (d3 < 0.0f);         \
    }

#define SWEEPQ(vv, pan, Qa, Qb, Qc, Qd)                                        \
    vv = fnma4(vv, pan.x, Qa); vv = fnma4(vv, pan.y, Qb);                      \
    vv = fnma4(vv, pan.z, Qc); vv = fnma4(vv, pan.w, Qd);

// One workgroup (512 thr) per frequency block. MERGED double-phase rank-4 LU:
// TWO rank-4 eliminations per barrier (12 phases + prologue). Within-wave DS
// ordering lets a consumer apply Q(k0), write back, re-read its own row's
// pan_B = group gp+1 (updated by lane gp+1 of the same half-wave), and apply
// Q(k0+4) -- no barrier in between. Producer (wave 0) per phase: sweep rows
// k0+8..15 with QA,QB (regs), factor panel(k0+8)->QA', publish, sweep rows
// k0+12..15 with QA', factor panel(k0+12)->QB', publish. Tail (k0=88):
// rows 96-99 swept + 4x4 diag-only panel.
__global__ __launch_bounds__(NT) void lu_logdet_kernel(const float* __restrict__ w,
                                                       const float* __restrict__ L,
                                                       float* __restrict__ out) {
    __shared__ float  a[BLK * P];
    __shared__ float4 qbuf[2][2][4][26];   // [parity][set A/B][panel row][col group]

    const int f    = blockIdx.x;
    const int tid  = threadIdx.x;
    const int wave = tid >> 6;
    const int sid  = tid >> 5;       // 16 half-wave streams
    const int g    = tid & 31;       // float4 column group
    const int gg   = (g < 25) ? g : 24;
    const int h    = sid & 1;        // half within wave

    // ---- load diag block f, fused transform: M[r][c] = s_r*D[r][c] + (r==c ? 1-s_r : 0)
    const float* base = L + (size_t)f * BLK * NTOT + (size_t)f * BLK;
    for (int q = tid; q < BLK * 25; q += NT) {         // 25 float4 per row
        const int r  = q / 25;
        const int c0 = (q - r * 25) * 4;
        const float4 v = *reinterpret_cast<const float4*>(base + (size_t)r * NTOT + c0);
        const float sv = 1.0f / (1.0f + expf(-w[f * BLK + r]));
        const float ds = 1.0f - sv;
        float4 m;
        m.x = sv * v.x + ((c0 + 0) == r ? ds : 0.0f);
        m.y = sv * v.y + ((c0 + 1) == r ? ds : 0.0f);
        m.z = sv * v.z + ((c0 + 2) == r ? ds : 0.0f);
        m.w = sv * v.w + ((c0 + 3) == r ? ds : 0.0f);
        *reinterpret_cast<float4*>(&a[r * P + c0]) = m;
    }
    __syncthreads();

    float mant = 1.0f;
    int   e2   = 0;
    int   lneg = 0;
    float4 Q0, Q1, Q2, Q3;

    // ---- prologue: everyone computes Q(0); producer also makes Q(4)
    PANEL_Q(0, 0)
    float4 QA0 = Q0, QA1 = Q1, QA2 = Q2, QA3 = Q3;   // Q(0) for phase 0
    float4 QB0, QB1, QB2, QB3;
    if (wave == 0) {
        // sweep rows 4..7 with Q(0) (h0: 4,6; h1: 5,7), write back
        const int r0 = 4 + h, r1 = 6 + h;
        float4 p0 = LD4(r0, 0), p1 = LD4(r1, 0);
        float4 v0 = LD4(r0, gg), v1 = LD4(r1, gg);
        SWEEPQ(v0, p0, QA0, QA1, QA2, QA3)
        SWEEPQ(v1, p1, QA0, QA1, QA2, QA3)
        if (g < 25) { LD4(r0, g) = v0; LD4(r1, g) = v1; }
        PANEL_Q(4, 1)
        QB0 = Q0; QB1 = Q1; QB2 = Q2; QB3 = Q3;
        if (g < 25) {
            qbuf[0][1][0][g] = QB0; qbuf[0][1][1][g] = QB1;
            qbuf[0][1][2][g] = QB2; qbuf[0][1][3][g] = QB3;
        }
    }
    __syncthreads();

    for (int k0 = 0; k0 <= 88; k0 += 8) {
        const int gp = k0 >> 2;
        const int ph = k0 >> 3;
        const int b  = ph & 1;
        const int nb = b ^ 1;

        if (wave == 0) {
            __builtin_amdgcn_s_setprio(1);
            // producer rows: h0: k0+8,10,12,14; h1: k0+9,11,13,15
            const int r0 = k0 + 8 + h,  r1 = k0 + 10 + h;
            const int r2 = k0 + 12 + h, r3 = k0 + 14 + h;
            const bool t23 = (r2 < BLK);
            float4 v0, v1, v2, v3;
            // ---- step 1: QA sweep + write back
            {
                const float4 p0 = LD4(r0, gp), p1 = LD4(r1, gp);
                v0 = LD4(r0, gg); v1 = LD4(r1, gg);
                SWEEPQ(v0, p0, QA0, QA1, QA2, QA3)
                SWEEPQ(v1, p1, QA0, QA1, QA2, QA3)
                if (g < 25) { LD4(r0, g) = v0; LD4(r1, g) = v1; }
                if (t23) {
                    const float4 p2 = LD4(r2, gp), p3 = LD4(r3, gp);
                    v2 = LD4(r2, gg); v3 = LD4(r3, gg);
                    SWEEPQ(v2, p2, QA0, QA1, QA2, QA3)
                    SWEEPQ(v3, p3, QA0, QA1, QA2, QA3)
                    if (g < 25) { LD4(r2, g) = v2; LD4(r3, g) = v3; }
                }
            }
            // ---- step 2: QB sweep (pan from gp+1, post-write) + write back
            {
                const float4 p0 = LD4(r0, gp + 1), p1 = LD4(r1, gp + 1);
                SWEEPQ(v0, p0, QB0, QB1, QB2, QB3)
                SWEEPQ(v1, p1, QB0, QB1, QB2, QB3)
                if (g < 25) { LD4(r0, g) = v0; LD4(r1, g) = v1; }
                if (t23) {
                    const float4 p2 = LD4(r2, gp + 1), p3 = LD4(r3, gp + 1);
                    SWEEPQ(v2, p2, QB0, QB1, QB2, QB3)
                    SWEEPQ(v3, p3, QB0, QB1, QB2, QB3)
                    if (g < 25) { LD4(r2, g) = v2; LD4(r3, g) = v3; }
                }
            }
            if (k0 < 88) {
                // ---- step 3: panel(k0+8) -> QA', publish
                PANEL_Q(k0 + 8, gp + 2)
                QA0 = Q0; QA1 = Q1; QA2 = Q2; QA3 = Q3;
                if (g < 25) {
                    qbuf[nb][0][0][g] = QA0; qbuf[nb][0][1][g] = QA1;
                    qbuf[nb][0][2][g] = QA2; qbuf[nb][0][3][g] = QA3;
                }
                // ---- step 4: rows k0+12..15 with QA', write back
                {
                    const float4 p2 = LD4(r2, gp + 2), p3 = LD4(r3, gp + 2);
                    SWEEPQ(v2, p2, QA0, QA1, QA2, QA3)
                    SWEEPQ(v3, p3, QA0, QA1, QA2, QA3)
                    if (g < 25) { LD4(r2, g) = v2; LD4(r3, g) = v3; }
                }
                // ---- step 5: panel(k0+12) -> QB', publish
                PANEL_Q(k0 + 12, gp + 3)
                QB0 = Q0; QB1 = Q1; QB2 = Q2; QB3 = Q3;
                if (g < 25) {
                    qbuf[nb][1][0][g] = QB0; qbuf[nb][1][1][g] = QB1;
                    qbuf[nb][1][2][g] = QB2; qbuf[nb][1][3][g] = QB3;
                }
            } else {
                // ---- tail: 4x4 panel rows 96..99, diag only (Q unused)
                PANEL_Q(96, 24)
            }
            __builtin_amdgcn_s_setprio(0);
        } else {
            // ---- consumers: fetch QA/QB, double rank-4 sweep of rows >= k0+16
            float4 CA0, CA1, CA2, CA3, CB0, CB1, CB2, CB3;
            if (k0 > 0) {
                CA0 = qbuf[b][0][0][gg]; CA1 = qbuf[b][0][1][gg];
                CA2 = qbuf[b][0][2][gg]; CA3 = qbuf[b][0][3][gg];
            } else {
                CA0 = QA0; CA1 = QA1; CA2 = QA2; CA3 = QA3;   // prologue Q(0)
            }
            CB0 = qbuf[b][1][0][gg]; CB1 = qbuf[b][1][1][gg];
            CB2 = qbuf[b][1][2][gg]; CB3 = qbuf[b][1][3][gg];
            if (g > gp && g < 25) {
                int i = k0 + 16 + (sid - 2);     // 14 streams
                for (; i + 14 < BLK; i += 28) {  // 2-deep pipelined
                    const int i2 = i + 14;
                    const float4 pa1 = LD4(i,  gp);
                    const float4 pa2 = LD4(i2, gp);
                    float4 va = LD4(i,  g);
                    float4 vb = LD4(i2, g);
                    SWEEPQ(va, pa1, CA0, CA1, CA2, CA3)
                    SWEEPQ(vb, pa2, CA0, CA1, CA2, CA3)
                    LD4(i,  g) = va;
                    LD4(i2, g) = vb;
                    const float4 pb1 = LD4(i,  gp + 1);   // post-write, wave-ordered
                    const float4 pb2 = LD4(i2, gp + 1);
                    SWEEPQ(va, pb1, CB0, CB1, CB2, CB3)
                    SWEEPQ(vb, pb2, CB0, CB1, CB2, CB3)
                    LD4(i,  g) = va;
                    LD4(i2, g) = vb;
                }
                for (; i < BLK; i += 14) {
                    const float4 pa = LD4(i, gp);
                    float4 v = LD4(i, g);
                    SWEEPQ(v, pa, CA0, CA1, CA2, CA3)
                    LD4(i, g) = v;
                    const float4 pb = LD4(i, gp + 1);
                    SWEEPQ(v, pb, CB0, CB1, CB2, CB3)
                    LD4(i, g) = v;
                }
            }
        }
        __syncthreads();
    }

    // ---- wave 0 lanes hold the full result redundantly; thread 0 publishes
    if (tid == 0) {
        float ld = logf(mant) + (float)e2 * 0.69314718055994531f;
        if ((lneg & 1) || !isfinite(ld)) ld = __int_as_float(0x7fc00000);  // NaN
        out[1 + f] = ld;
        atomicAdd(out, ld);   // out[0] zeroed via memset before launch; NaN propagates
    }
}

extern "C" void kernel_launch(void* const* d_in, const int* in_sizes, int n_in,
                              void* d_out, int out_size, void* d_ws, size_t ws_size,
                              hipStream_t stream) {
    const float* w = (const float*)d_in[0];   // weights (12800,) f32
    const float* L = (const float*)d_in[1];   // L_kernel (12800,12800) f32
    float* out = (float*)d_out;               // [0]=sum, [1..128]=logdets
    hipMemsetAsync(d_out, 0, sizeof(float), stream);   // zero the atomic accumulator
    lu_logdet_kernel<<<NF, NT, 0, stream>>>(w, L, out);
}

// Round 17
// 30.316 us; speedup vs baseline: 1.1030x; 1.1030x over previous
//
#include <hip/hip_runtime.h>
#include <math.h>

#define BLK 100          // BLOCK
#define NF  128          // N_freqs
#define NTOT (NF * BLK)  // 12800
#define P   104          // LDS pitch (floats): rows 16B-aligned (416B)
#define NT  512          // 8 waves = 2 waves/SIMD (measured best)

__device__ __forceinline__ float4 fnma4(float4 v, float s, const float4 p) {
    v.x -= s * p.x; v.y -= s * p.y; v.z -= s * p.z; v.w -= s * p.w; return v;
}
__device__ __forceinline__ float4 mul4(float4 v, float s) {
    v.x *= s; v.y *= s; v.z *= s; v.w *= s; return v;
}

#define LD4(r, c4) (*reinterpret_cast<float4*>(&a[(r) * P + 4 * (c4)]))

// 4x4 panel at rows kb..kb+3, panel col group gq, lane col group gg ->
// Q0..Q3 = panel^-1 * P_raw; accumulates mant/e2/lneg. Reads LDS, per-lane ops.
#define PANEL_Q(kb, gq)                                                        \
    {                                                                          \
        float4 pp0 = LD4((kb) + 0, (gq));                                      \
        float4 pp1 = LD4((kb) + 1, (gq));                                      \
        float4 pp2 = LD4((kb) + 2, (gq));                                      \
        float4 pp3 = LD4((kb) + 3, (gq));                                      \
        float4 P0  = LD4((kb) + 0, gg);                                        \
        float4 P1  = LD4((kb) + 1, gg);                                        \
        float4 P2  = LD4((kb) + 2, gg);                                        \
        float4 P3  = LD4((kb) + 3, gg);                                        \
        const float d0 = pp0.x, r0i = 1.0f / d0;                               \
        float l;                                                               \
        l = pp1.x * r0i;  pp1 = fnma4(pp1, l, pp0);  P1 = fnma4(P1, l, P0);    \
        const float d1 = pp1.y, r1i = 1.0f / d1;                               \
        l = pp2.x * r0i;  pp2 = fnma4(pp2, l, pp0);  P2 = fnma4(P2, l, P0);    \
        l = pp2.y * r1i;  pp2 = fnma4(pp2, l, pp1);  P2 = fnma4(P2, l, P1);    \
        const float d2 = pp2.z, r2i = 1.0f / d2;                               \
        l = pp3.x * r0i;  pp3 = fnma4(pp3, l, pp0);  P3 = fnma4(P3, l, P0);    \
        l = pp3.y * r1i;  pp3 = fnma4(pp3, l, pp1);  P3 = fnma4(P3, l, P1);    \
        l = pp3.z * r2i;  pp3 = fnma4(pp3, l, pp2);  P3 = fnma4(P3, l, P2);    \
        const float d3 = pp3.w, r3i = 1.0f / d3;                               \
        Q3 = mul4(P3, r3i);                                                    \
        Q2 = mul4(fnma4(P2, pp2.w, Q3), r2i);                                  \
        Q1 = mul4(fnma4(fnma4(P1, pp1.z, Q2), pp1.w, Q3), r1i);                \
        Q0 = mul4(fnma4(fnma4(fnma4(P0, pp0.y, Q1), pp0.z, Q2), pp0.w, Q3), r0i); \
        mant *= d0 * d1 * d2 * d3;                                             \
        { int t_; mant = frexpf(mant, &t_); e2 += t_; }                        \
        lneg += (d0 < 0.0f) + (d1 < 0.0f) + (d2 < 0.0f) + (d3 < 0.0f);         \
    }

#define SWEEP4(vv, pan)                                                        \
    vv = fnma4(vv, pan.x, Q0); vv = fnma4(vv, pan.y, Q1);                      \
    vv = fnma4(vv, pan.z, Q2); vv = fnma4(vv, pan.w, Q3);

// One workgroup (512 thr) per frequency block. Rank-4 blocked non-pivoted LU
// in LDS, 1 barrier/phase (21 barriered phases), producer/consumer split:
//   wave 0 (producer): urgent-sweep rows k0+4..7 with Q(k0), factor
//     panel(k0+4) -> Q(k0+4), publish to qbuf (double-buffered).
//   waves 1-7 (consumers): load Q(k0), bulk-sweep rows k0+8..99 over 14
//     streams, 4-deep software-pipelined LDS loads.
// TAIL (after k0=80): wave 0 alone finishes cols 84..99 barrier-free
// (12+8+4 row sweeps + 3 panel factorizations, all wave-local in-order DS).
__global__ __launch_bounds__(NT) void lu_logdet_kernel(const float* __restrict__ w,
                                                       const float* __restrict__ L,
                                                       float* __restrict__ out) {
    __shared__ float  a[BLK * P];
    __shared__ float4 qbuf[2][4][26];

    const int f    = blockIdx.x;
    const int tid  = threadIdx.x;
    const int wave = tid >> 6;
    const int sid  = tid >> 5;       // 16 half-wave streams
    const int g    = tid & 31;       // float4 column group
    const int gg   = (g < 25) ? g : 24;
    const int h    = sid & 1;        // half within wave

    // ---- load diag block f, fused transform: M[r][c] = s_r*D[r][c] + (r==c ? 1-s_r : 0)
    const float* base = L + (size_t)f * BLK * NTOT + (size_t)f * BLK;
    for (int q = tid; q < BLK * 25; q += NT) {         // 25 float4 per row
        const int r  = q / 25;
        const int c0 = (q - r * 25) * 4;
        const float4 v = *reinterpret_cast<const float4*>(base + (size_t)r * NTOT + c0);
        const float sv = 1.0f / (1.0f + expf(-w[f * BLK + r]));
        const float ds = 1.0f - sv;
        float4 m;
        m.x = sv * v.x + ((c0 + 0) == r ? ds : 0.0f);
        m.y = sv * v.y + ((c0 + 1) == r ? ds : 0.0f);
        m.z = sv * v.z + ((c0 + 2) == r ? ds : 0.0f);
        m.w = sv * v.w + ((c0 + 3) == r ? ds : 0.0f);
        *reinterpret_cast<float4*>(&a[r * P + c0]) = m;
    }
    __syncthreads();

    float mant = 1.0f;
    int   e2   = 0;
    int   lneg = 0;
    float4 Q0, Q1, Q2, Q3;

    // ---- prologue: everyone computes Q(0) redundantly
    PANEL_Q(0, 0)

    // ---- barriered phases: k0 = 0..80
    for (int k0 = 0; k0 <= 80; k0 += 4) {
        const int gp = k0 >> 2;
        const int b  = gp & 1;
        const int nb = b ^ 1;

        if (wave == 0) {
            __builtin_amdgcn_s_setprio(1);
            // urgent sweep: rows k0+4..k0+7 (h0: +4,+6; h1: +5,+7)
            if (g > gp && g < 25) {
                const int i1 = k0 + 4 + h;
                const int i2 = k0 + 6 + h;
                const float4 pan1 = LD4(i1, gp);
                const float4 pan2 = LD4(i2, gp);
                float4 v1 = LD4(i1, g);
                float4 v2 = LD4(i2, g);
                SWEEP4(v1, pan1)
                SWEEP4(v2, pan2)
                LD4(i1, g) = v1;
                LD4(i2, g) = v2;
            }
            // panel(k0+4) from rows this wave just swept (DS in-order)
            PANEL_Q(k0 + 4, gp + 1)
            if (g < 25) {
                qbuf[nb][0][g] = Q0; qbuf[nb][1][g] = Q1;
                qbuf[nb][2][g] = Q2; qbuf[nb][3][g] = Q3;
            }
            __builtin_amdgcn_s_setprio(0);
        } else {
            // consumers: fetch Q(k0) (prologue regs at k0==0), bulk sweep
            if (k0 > 0) {
                Q0 = qbuf[b][0][gg]; Q1 = qbuf[b][1][gg];
                Q2 = qbuf[b][2][gg]; Q3 = qbuf[b][3][gg];
            }
            if (g > gp && g < 25) {
                int i = k0 + 8 + (sid - 2);      // 14 streams
                for (; i + 42 < BLK; i += 56) {  // 4-deep pipelined
                    const float4 pa = LD4(i,      gp);
                    const float4 pb = LD4(i + 14, gp);
                    const float4 pc = LD4(i + 28, gp);
                    const float4 pd = LD4(i + 42, gp);
                    float4 va = LD4(i,      g);
                    float4 vb = LD4(i + 14, g);
                    float4 vc = LD4(i + 28, g);
                    float4 vd = LD4(i + 42, g);
                    SWEEP4(va, pa) SWEEP4(vb, pb) SWEEP4(vc, pc) SWEEP4(vd, pd)
                    LD4(i,      g) = va;
                    LD4(i + 14, g) = vb;
                    LD4(i + 28, g) = vc;
                    LD4(i + 42, g) = vd;
                }
                for (; i + 14 < BLK; i += 28) {  // 2-deep
                    const float4 pa = LD4(i,      gp);
                    const float4 pb = LD4(i + 14, gp);
                    float4 va = LD4(i,      g);
                    float4 vb = LD4(i + 14, g);
                    SWEEP4(va, pa) SWEEP4(vb, pb)
                    LD4(i,      g) = va;
                    LD4(i + 14, g) = vb;
                }
                for (; i < BLK; i += 14) {
                    const float4 pa = LD4(i, gp);
                    float4 va = LD4(i, g);
                    SWEEP4(va, pa)
                    LD4(i, g) = va;
                }
            }
        }
        __syncthreads();
    }

    // ---- barrier-free tail: wave 0 finishes cols 84..99 alone.
    // State here: rows >= 88 updated through elim 83 (consumers, phase 80);
    // rows 84..87 factored (panel(84), Q(84) in wave-0 regs, diag recorded).
    if (wave == 0) {
        // step 1: sweep rows 88..99 with Q(84)  (pan col group 21)
        if (g > 21 && g < 25) {
            #pragma unroll
            for (int j = 0; j < 6; ++j) {
                const int r = 88 + 2 * j + h;
                const float4 pan = LD4(r, 21);
                float4 v = LD4(r, g);
                SWEEP4(v, pan)
                LD4(r, g) = v;
            }
        }
        PANEL_Q(88, 22)
        // step 2: sweep rows 92..99 with Q(88)  (pan col group 22)
        if (g > 22 && g < 25) {
            #pragma unroll
            for (int j = 0; j < 4; ++j) {
                const int r = 92 + 2 * j + h;
                const float4 pan = LD4(r, 22);
                float4 v = LD4(r, g);
                SWEEP4(v, pan)
                LD4(r, g) = v;
            }
        }
        PANEL_Q(92, 23)
        // step 3: sweep rows 96..99 with Q(92)  (pan col group 23)
        if (g > 23 && g < 25) {
            #pragma unroll
            for (int j = 0; j < 2; ++j) {
                const int r = 96 + 2 * j + h;
                const float4 pan = LD4(r, 23);
                float4 v = LD4(r, g);
                SWEEP4(v, pan)
                LD4(r, g) = v;
            }
        }
        PANEL_Q(96, 24)        // diag 96..99 (Q unused)
    }

    // ---- thread 0 (wave 0) holds the full result; publish (no barrier needed)
    if (tid == 0) {
        float ld = logf(mant) + (float)e2 * 0.69314718055994531f;
        if ((lneg & 1) || !isfinite(ld)) ld = __int_as_float(0x7fc00000);  // NaN
        out[1 + f] = ld;
        atomicAdd(out, ld);   // out[0] zeroed via memset before launch; NaN propagates
    }
}

extern "C" void kernel_launch(void* const* d_in, const int* in_sizes, int n_in,
                              void* d_out, int out_size, void* d_ws, size_t ws_size,
                              hipStream_t stream) {
    const float* w = (const float*)d_in[0];   // weights (12800,) f32
    const float* L = (const float*)d_in[1];   // L_kernel (12800,12800) f32
    float* out = (float*)d_out;               // [0]=sum, [1..128]=logdets
    hipMemsetAsync(d_out, 0, sizeof(float), stream);   // zero the atomic accumulator
    lu_logdet_kernel<<<NF, NT, 0, stream>>>(w, L, out);
}